// Round 1
// baseline (343.044 us; speedup 1.0000x reference)
//
#include <hip/hip_runtime.h>

#define B_  32
#define N_  1024
#define D_  768
#define K_  768          // masked patches per batch (MASK_RATIO * N)
#define U_  256          // unmasked patches per batch
#define D4_ 192          // D / 4

// ---------------------------------------------------------------------------
// Kernel A: stable rank of noise within each batch row, scatter mask flag.
// key = (ieee_bits(noise) << 10) | index : noise in [0,1) so uint-bit order ==
// float order; low 10 bits give the stable (by-index) tie break. rank(i) is a
// bijection, so each maskinfo slot is written exactly once.
// j-loop address is wave-uniform -> compiler emits s_load (scalar pipe),
// leaving ~2 VALU inst per compare.
// ---------------------------------------------------------------------------
__global__ __launch_bounds__(128) void rank_scatter(const float* __restrict__ noise,
                                                    int* __restrict__ maskinfo) {
    const int b = blockIdx.x >> 3;                       // 8 blocks per batch
    const int i = ((blockIdx.x & 7) << 7) + threadIdx.x; // this thread's element
    const float* __restrict__ row = noise + b * N_;

    const unsigned int bi = __float_as_uint(row[i]);
    const unsigned long long ki = ((unsigned long long)bi << 10) | (unsigned int)i;

    int r = 0;
#pragma unroll 16
    for (int j = 0; j < N_; ++j) {
        const unsigned int bj = __float_as_uint(row[j]);
        const unsigned long long kj = ((unsigned long long)bj << 10) | (unsigned int)j;
        r += (kj < ki) ? 1 : 0;
    }
    maskinfo[b * N_ + r] = (i < K_) ? 1 : 0;
}

// ---------------------------------------------------------------------------
// Kernel B: per-batch prefix over the mask via ballot+popcount; emit the
// ascending masked/unmasked index lists (float, values < 1024 are exact) and
// rewrite maskinfo in place: -1 if masked, else position within the unmasked
// (compacted) list.
// ---------------------------------------------------------------------------
__global__ __launch_bounds__(1024) void index_lists(int* __restrict__ maskinfo,
                                                    float* __restrict__ masked_idx,
                                                    float* __restrict__ unmasked_idx) {
    const int b   = blockIdx.x;
    const int tid = threadIdx.x;
    const bool m  = maskinfo[b * N_ + tid] != 0;

    const unsigned long long bal = __ballot(m);
    const int lane = tid & 63;
    const int wave = tid >> 6;

    __shared__ int wsum[16];
    const int inwave = __popcll(bal & ((1ull << lane) - 1ull));
    if (lane == 0) wsum[wave] = __popcll(bal);
    __syncthreads();

    int off = 0;
    for (int w = 0; w < wave; ++w) off += wsum[w];
    const int p = off + inwave;                   // # masked strictly before tid

    if (m) {
        masked_idx[b * K_ + p] = (float)tid;
        maskinfo[b * N_ + tid] = -1;
    } else {
        const int u = tid - p;                    // # unmasked strictly before tid
        unmasked_idx[b * U_ + u] = (float)tid;
        maskinfo[b * N_ + tid] = u;
    }
}

// ---------------------------------------------------------------------------
// Kernel C: fused expand. block = 192 threads = one row of 192 float4 = exactly
// 3 waves, so the per-row mask branch is wave-uniform (no divergence) and
// maskinfo[row] is a uniform scalar load. Masked rows never touch patch data
// (saves 75% of input reads); unmasked rows are read once and feed both
// with_mask and unmasked_patches_only.
// ---------------------------------------------------------------------------
#define ROWS_ 8
__global__ __launch_bounds__(192) void expand(const float4* __restrict__ patch,
                                              const float4* __restrict__ memb,
                                              const int* __restrict__ maskinfo,
                                              float4* __restrict__ with_mask,
                                              float4* __restrict__ unmasked_only,
                                              float4* __restrict__ bool_exp) {
    const int tid = threadIdx.x;
    const float4 me   = memb[tid];                // 3 KB, L1-resident
    const float4 ONE  = make_float4(1.f, 1.f, 1.f, 1.f);
    const float4 ZERO = make_float4(0.f, 0.f, 0.f, 0.f);

    const int base = blockIdx.x * ROWS_;
#pragma unroll
    for (int it = 0; it < ROWS_; ++it) {
        const int rowi = base + it;
        const int info = maskinfo[rowi];          // uniform -> s_load
        const int o    = rowi * D4_ + tid;        // fits in int (max ~6.3M)
        if (info < 0) {
            with_mask[o] = me;
            bool_exp[o]  = ONE;
        } else {
            const float4 p = patch[o];
            with_mask[o] = p;
            bool_exp[o]  = ZERO;
            const int b  = rowi >> 10;            // row / N_
            unmasked_only[(b * U_ + info) * D4_ + tid] = p;
        }
    }
}

extern "C" void kernel_launch(void* const* d_in, const int* in_sizes, int n_in,
                              void* d_out, int out_size, void* d_ws, size_t ws_size,
                              hipStream_t stream) {
    const float* patch = (const float*)d_in[0];   // (B, N, D) f32
    const float* noise = (const float*)d_in[1];   // (B, N) f32
    const float* memb  = (const float*)d_in[2];   // (D,) f32

    float* out  = (float*)d_out;
    float* out0 = out;                             // with_mask           B*N*D
    float* out1 = out0 + (size_t)B_ * N_ * D_;     // unmasked_patches    B*U*D
    float* out2 = out1 + (size_t)B_ * U_ * D_;     // bool_mask_expanded  B*N*D
    float* out3 = out2 + (size_t)B_ * N_ * D_;     // masked_indices      B*K
    float* out4 = out3 + (size_t)B_ * K_;          // unmasked_indices    B*U

    int* maskinfo = (int*)d_ws;                    // B*N ints = 128 KB

    rank_scatter<<<B_ * 8, 128, 0, stream>>>(noise, maskinfo);
    index_lists<<<B_, 1024, 0, stream>>>(maskinfo, out3, out4);
    expand<<<(B_ * N_) / ROWS_, 192, 0, stream>>>(
        (const float4*)patch, (const float4*)memb, maskinfo,
        (float4*)out0, (float4*)out1, (float4*)out2);
}

// Round 3
// 310.383 us; speedup vs baseline: 1.1052x; 1.1052x over previous
//
#include <hip/hip_runtime.h>

#define B_  32
#define N_  1024
#define D_  768
#define K_  768          // masked patches per batch (MASK_RATIO * N)
#define U_  256          // unmasked patches per batch
#define D4_ 192          // D / 4

// native 4-float vector for __builtin_nontemporal_store (HIP float4 is a
// class and the builtin rejects it)
typedef float vfloat4 __attribute__((ext_vector_type(4)));

__device__ __forceinline__ void nt_store4(float4* p, float4 v) {
    vfloat4 nv = { v.x, v.y, v.z, v.w };
    __builtin_nontemporal_store(nv, reinterpret_cast<vfloat4*>(p));
}

// ---------------------------------------------------------------------------
// Kernel A: stable rank of noise within each batch row, scatter mask flag.
// key = (ieee_bits(noise) << 10) | index : noise in [0,1) so uint-bit order ==
// float order; low 10 bits give the stable (by-index) tie break. rank(i) is a
// bijection, so each maskinfo slot is written exactly once.
// R2: row keys staged in LDS (8 KB) — j-loop reads are same-address LDS
// broadcasts (conflict-free) instead of per-iteration global loads.
// ---------------------------------------------------------------------------
__global__ __launch_bounds__(128) void rank_scatter(const float* __restrict__ noise,
                                                    int* __restrict__ maskinfo) {
    __shared__ unsigned long long keys[N_];
    const int b    = blockIdx.x >> 3;                 // 8 blocks per batch
    const int base = (blockIdx.x & 7) << 7;
    const float* __restrict__ row = noise + b * N_;

    for (int j = threadIdx.x; j < N_; j += 128)
        keys[j] = ((unsigned long long)__float_as_uint(row[j]) << 10) | (unsigned)j;
    __syncthreads();

    const int i = base + threadIdx.x;
    const unsigned long long ki = keys[i];
    int r = 0;
#pragma unroll 16
    for (int j = 0; j < N_; ++j)
        r += (keys[j] < ki) ? 1 : 0;

    maskinfo[b * N_ + r] = (i < K_) ? 1 : 0;
}

// ---------------------------------------------------------------------------
// Kernel B: per-batch prefix over the mask via ballot+popcount; emit the
// ascending masked/unmasked index lists (float, values < 1024 are exact) and
// rewrite maskinfo in place: -1 if masked, else position within the unmasked
// (compacted) list.
// ---------------------------------------------------------------------------
__global__ __launch_bounds__(1024) void index_lists(int* __restrict__ maskinfo,
                                                    float* __restrict__ masked_idx,
                                                    float* __restrict__ unmasked_idx) {
    const int b   = blockIdx.x;
    const int tid = threadIdx.x;
    const bool m  = maskinfo[b * N_ + tid] != 0;

    const unsigned long long bal = __ballot(m);
    const int lane = tid & 63;
    const int wave = tid >> 6;

    __shared__ int wsum[16];
    const int inwave = __popcll(bal & ((1ull << lane) - 1ull));
    if (lane == 0) wsum[wave] = __popcll(bal);
    __syncthreads();

    int off = 0;
    for (int w = 0; w < wave; ++w) off += wsum[w];
    const int p = off + inwave;                   // # masked strictly before tid

    if (m) {
        masked_idx[b * K_ + p] = (float)tid;
        maskinfo[b * N_ + tid] = -1;
    } else {
        const int u = tid - p;                    // # unmasked strictly before tid
        unmasked_idx[b * U_ + u] = (float)tid;
        maskinfo[b * N_ + tid] = u;
    }
}

// ---------------------------------------------------------------------------
// Kernel C: fused expand. block = 192 threads = one row of 192 float4 = exactly
// 3 waves, so the per-row mask branch is wave-uniform (no divergence) and
// maskinfo[row] is a uniform scalar load. Masked rows never touch patch data
// (saves 75% of input reads); unmasked rows are read once and feed both
// with_mask and unmasked_patches_only.
// R2: nontemporal stores on all three streamed outputs (written once, never
// re-read in-kernel) to keep L2 clean for patch reads; 16 rows per block.
// ---------------------------------------------------------------------------
#define ROWS_ 16
__global__ __launch_bounds__(192) void expand(const float4* __restrict__ patch,
                                              const float4* __restrict__ memb,
                                              const int* __restrict__ maskinfo,
                                              float4* __restrict__ with_mask,
                                              float4* __restrict__ unmasked_only,
                                              float4* __restrict__ bool_exp) {
    const int tid = threadIdx.x;
    const float4 me   = memb[tid];                // 3 KB, L1-resident
    const float4 ONE  = make_float4(1.f, 1.f, 1.f, 1.f);
    const float4 ZERO = make_float4(0.f, 0.f, 0.f, 0.f);

    const int base = blockIdx.x * ROWS_;
#pragma unroll
    for (int it = 0; it < ROWS_; ++it) {
        const int rowi = base + it;
        const int info = maskinfo[rowi];          // uniform -> scalar load
        const int o    = rowi * D4_ + tid;        // fits in int (max ~6.3M)
        if (info < 0) {
            nt_store4(&with_mask[o], me);
            nt_store4(&bool_exp[o],  ONE);
        } else {
            const float4 p = patch[o];
            nt_store4(&with_mask[o], p);
            nt_store4(&bool_exp[o],  ZERO);
            const int b = rowi >> 10;             // row / N_
            nt_store4(&unmasked_only[(b * U_ + info) * D4_ + tid], p);
        }
    }
}

extern "C" void kernel_launch(void* const* d_in, const int* in_sizes, int n_in,
                              void* d_out, int out_size, void* d_ws, size_t ws_size,
                              hipStream_t stream) {
    const float* patch = (const float*)d_in[0];   // (B, N, D) f32
    const float* noise = (const float*)d_in[1];   // (B, N) f32
    const float* memb  = (const float*)d_in[2];   // (D,) f32

    float* out  = (float*)d_out;
    float* out0 = out;                             // with_mask           B*N*D
    float* out1 = out0 + (size_t)B_ * N_ * D_;     // unmasked_patches    B*U*D
    float* out2 = out1 + (size_t)B_ * U_ * D_;     // bool_mask_expanded  B*N*D
    float* out3 = out2 + (size_t)B_ * N_ * D_;     // masked_indices      B*K
    float* out4 = out3 + (size_t)B_ * K_;          // unmasked_indices    B*U

    int* maskinfo = (int*)d_ws;                    // B*N ints = 128 KB

    rank_scatter<<<B_ * 8, 128, 0, stream>>>(noise, maskinfo);
    index_lists<<<B_, 1024, 0, stream>>>(maskinfo, out3, out4);
    expand<<<(B_ * N_) / ROWS_, 192, 0, stream>>>(
        (const float4*)patch, (const float4*)memb, maskinfo,
        (float4*)out0, (float4*)out1, (float4*)out2);
}